// Round 1
// baseline (1039.270 us; speedup 1.0000x reference)
//
#include <hip/hip_runtime.h>

// Counting-sort + LDS accumulation (no global atomics anywhere).
// R4 -> R5: k_accum was stall-bound (VGPR_Count=16 => compiler serialized all
// loads; VALUBusy 1.75%, HBM 5%, nothing saturated).
//   - k_accum: explicit T=8 register batch (8 nt tuple loads -> 8 independent
//     charge gathers -> 32 ds_adds), sched_barrier to keep clusters; ~8x MLP.
//   - nontemporal tuple loads + partials stores (keep charges L2-resident).
//   - plane-major LDS accumulator (stride 1056 == 0 mod 32): atomics spread
//     over 32 banks instead of 8.

#define BLOCK   256
#define NBLK    1024       // edge chunks for hist/scatter (== rowscan width)
#define NBLK_LG 10
#define AB_LOG  10
#define A_B     1024       // atoms per bucket
#define PLANE   1056       // A_B + 32 pad; 1056 % 32 == 0 -> same bank map per plane
#define MAXNB   256

static __device__ __forceinline__ unsigned long long nt_u64(const void* p) {
    return __builtin_nontemporal_load((const unsigned long long*)p);
}
static __device__ __forceinline__ float nt_f32(const float* p) {
    return __builtin_nontemporal_load(p);
}
typedef float v4f __attribute__((ext_vector_type(4)));
static __device__ __forceinline__ void nt_store_f4(float4 v, float4* p) {
    v4f x; x.x = v.x; x.y = v.y; x.z = v.z; x.w = v.w;
    __builtin_nontemporal_store(x, (v4f*)p);
}

// ---- K1: per-block histogram over buckets -------------------------------
__global__ __launch_bounds__(BLOCK) void k_hist(
    const int2* __restrict__ nbr, int* __restrict__ blk_hist,
    int n_edges, int nb)
{
    __shared__ int h[MAXNB];
    for (int i = threadIdx.x; i < nb; i += blockDim.x) h[i] = 0;
    __syncthreads();
    int per = (n_edges + gridDim.x - 1) / gridDim.x;
    int lo = blockIdx.x * per;
    int hi = min(lo + per, n_edges);
    #pragma unroll 4
    for (int e = lo + threadIdx.x; e < hi; e += blockDim.x) {
        unsigned long long v = nt_u64(&nbr[e]);
        int ix = (int)(v & 0xffffffffu);
        int iy = (int)(v >> 32);
        atomicAdd(&h[ix >> AB_LOG], 1);
        atomicAdd(&h[iy >> AB_LOG], 1);
    }
    __syncthreads();
    for (int i = threadIdx.x; i < nb; i += blockDim.x)
        blk_hist[i * NBLK + blockIdx.x] = h[i];
}

// ---- K2: exclusive scan of each bucket's row (NBLK entries) -------------
__global__ __launch_bounds__(NBLK) void k_rowscan(
    const int* __restrict__ blk_hist, int* __restrict__ offs,
    int* __restrict__ totals)
{
    __shared__ int a[NBLK];
    int b = blockIdx.x, t = threadIdx.x;
    int v = blk_hist[b * NBLK + t];
    a[t] = v;
    __syncthreads();
    for (int off = 1; off < NBLK; off <<= 1) {
        int x = (t >= off) ? a[t - off] : 0;
        __syncthreads();
        a[t] += x;
        __syncthreads();
    }
    offs[b * NBLK + t] = a[t] - v;       // exclusive within bucket
    if (t == NBLK - 1) totals[b] = a[t];
}

// ---- K3: bucket bases (parallel LDS scan, one block) --------------------
__global__ __launch_bounds__(MAXNB) void k_bases(
    const int* __restrict__ totals, int* __restrict__ bases, int nb)
{
    __shared__ int a[MAXNB];
    int t = threadIdx.x;
    int v = (t < nb) ? totals[t] : 0;
    a[t] = v;
    __syncthreads();
    for (int off = 1; off < MAXNB; off <<= 1) {
        int x = (t >= off) ? a[t - off] : 0;
        __syncthreads();
        a[t] += x;
        __syncthreads();
    }
    if (t < nb) bases[t] = a[t] - v;
}

// ---- K4: offs[i] += bases[i / NBLK] -------------------------------------
__global__ void k_addbase(int* __restrict__ offs, const int* __restrict__ bases, int n)
{
    int i = blockIdx.x * blockDim.x + threadIdx.x;
    if (i < n) offs[i] += bases[i >> NBLK_LG];
}

// ---- K5: counting-sort scatter of tuples --------------------------------
__global__ __launch_bounds__(BLOCK) void k_scatter(
    const int2* __restrict__ nbr, const float* __restrict__ dist,
    const int* __restrict__ offs, uint2* __restrict__ tuples,
    int n_edges, int nb)
{
    __shared__ int cur[MAXNB];
    for (int i = threadIdx.x; i < nb; i += blockDim.x)
        cur[i] = offs[i * NBLK + blockIdx.x];
    __syncthreads();
    int per = (n_edges + gridDim.x - 1) / gridDim.x;
    int lo = blockIdx.x * per;
    int hi = min(lo + per, n_edges);
    #pragma unroll 2
    for (int e = lo + threadIdx.x; e < hi; e += blockDim.x) {
        unsigned long long v = nt_u64(&nbr[e]);
        int ix = (int)(v & 0xffffffffu);
        int iy = (int)(v >> 32);
        float w = 0.5f / nt_f32(&dist[e]);
        unsigned wb = __float_as_uint(w);
        int pi = atomicAdd(&cur[ix >> AB_LOG], 1);
        tuples[pi] = make_uint2((unsigned)(ix & (A_B - 1)) | ((unsigned)iy << AB_LOG), wb);
        int pj = atomicAdd(&cur[iy >> AB_LOG], 1);
        tuples[pj] = make_uint2((unsigned)(iy & (A_B - 1)) | ((unsigned)ix << AB_LOG), wb);
    }
}

// ---- K6: per-(bucket,slice) LDS accumulation, T=8 register batch --------
__global__ __launch_bounds__(BLOCK) void k_accum(
    const uint2* __restrict__ tuples, const float4* __restrict__ charges,
    const int* __restrict__ bases, const int* __restrict__ totals,
    float4* __restrict__ partials, int nslice)
{
    __shared__ float acc[4 * PLANE];   // plane-major: acc[ch*PLANE + local]
    int b = blockIdx.x / nslice;
    int s = blockIdx.x - b * nslice;
    for (int i = threadIdx.x; i < 4 * PLANE; i += BLOCK) acc[i] = 0.f;
    __syncthreads();
    int start = bases[b], cnt = totals[b];
    int lo = start + (int)((long long)cnt * s / nslice);
    int hi = start + (int)((long long)cnt * (s + 1) / nslice);

    const int T = 8;
    int p = lo + threadIdx.x;
    for (; p + (T - 1) * BLOCK < hi; p += T * BLOCK) {
        unsigned long long t[T];
        float4 c[T];
        // cluster 1: 8 independent nt tuple loads
        #pragma unroll
        for (int k = 0; k < T; ++k)
            t[k] = nt_u64(&tuples[p + k * BLOCK]);
        __builtin_amdgcn_sched_barrier(0);
        // cluster 2: 8 independent charge gathers (L2-resident, high MLP)
        #pragma unroll
        for (int k = 0; k < T; ++k)
            c[k] = charges[(unsigned)(t[k] & 0xffffffffu) >> AB_LOG];
        __builtin_amdgcn_sched_barrier(0);
        // cluster 3: 32 ds_add_f32, spread over all 32 banks
        #pragma unroll
        for (int k = 0; k < T; ++k) {
            float w = __uint_as_float((unsigned)(t[k] >> 32));
            int d = (int)(t[k] & (A_B - 1));
            atomicAdd(&acc[d],             c[k].x * w);
            atomicAdd(&acc[PLANE + d],     c[k].y * w);
            atomicAdd(&acc[2 * PLANE + d], c[k].z * w);
            atomicAdd(&acc[3 * PLANE + d], c[k].w * w);
        }
    }
    for (; p < hi; p += BLOCK) {
        unsigned long long t = nt_u64(&tuples[p]);
        float4 c = charges[(unsigned)(t & 0xffffffffu) >> AB_LOG];
        float w = __uint_as_float((unsigned)(t >> 32));
        int d = (int)(t & (A_B - 1));
        atomicAdd(&acc[d],             c.x * w);
        atomicAdd(&acc[PLANE + d],     c.y * w);
        atomicAdd(&acc[2 * PLANE + d], c.z * w);
        atomicAdd(&acc[3 * PLANE + d], c.w * w);
    }
    __syncthreads();
    float4* outp = partials + (size_t)blockIdx.x * A_B;
    for (int i = threadIdx.x; i < A_B; i += BLOCK) {
        float4 v = make_float4(acc[i], acc[PLANE + i],
                               acc[2 * PLANE + i], acc[3 * PLANE + i]);
        nt_store_f4(v, &outp[i]);
    }
}

// ---- K7: reduce nslice partial images -> out ----------------------------
__global__ void k_final(const float4* __restrict__ partials,
                        float4* __restrict__ out, int n_atoms, int nslice)
{
    int a = blockIdx.x * blockDim.x + threadIdx.x;
    if (a >= n_atoms) return;
    int b = a >> AB_LOG;
    int local = a & (A_B - 1);
    const float4* p = partials + (size_t)(b * nslice) * A_B + local;
    float4 r = make_float4(0.f, 0.f, 0.f, 0.f);
    for (int s = 0; s < nslice; ++s) {
        float4 t = p[(size_t)s * A_B];
        r.x += t.x; r.y += t.y; r.z += t.z; r.w += t.w;
    }
    out[a] = r;
}

// ---- fallback (ws too small): agent-scope atomics, correct but 5 ms -----
__global__ __launch_bounds__(BLOCK) void edge_scatter_agent(
    const float4* __restrict__ charges, const int2* __restrict__ nbr,
    const float* __restrict__ dist, float* __restrict__ out, int n_edges)
{
    int e = blockIdx.x * blockDim.x + threadIdx.x;
    if (e >= n_edges) return;
    int2 ij = nbr[e];
    float w = 0.5f / dist[e];
    float4 cj = charges[ij.y];
    float4 ci = charges[ij.x];
    float* oi = out + (size_t)ij.x * 4;
    float* oj = out + (size_t)ij.y * 4;
    atomicAdd(oi + 0, cj.x * w); atomicAdd(oi + 1, cj.y * w);
    atomicAdd(oi + 2, cj.z * w); atomicAdd(oi + 3, cj.w * w);
    atomicAdd(oj + 0, ci.x * w); atomicAdd(oj + 1, ci.y * w);
    atomicAdd(oj + 2, ci.z * w); atomicAdd(oj + 3, ci.w * w);
}

extern "C" void kernel_launch(void* const* d_in, const int* in_sizes, int n_in,
                              void* d_out, int out_size, void* d_ws, size_t ws_size,
                              hipStream_t stream)
{
    // inputs: charges, cell, positions, neighbor_indices, neighbor_distances
    const float4* charges = (const float4*)d_in[0];
    const int2*   nbr     = (const int2*)d_in[3];
    const float*  dist    = (const float*)d_in[4];

    int n_edges = in_sizes[4];
    int n_atoms = out_size / 4;
    int nb = (n_atoms + A_B - 1) >> AB_LOG;     // 196 for 200000 atoms

    size_t n_pairs = (size_t)2 * n_edges;
    char*  w   = (char*)d_ws;
    size_t off = 0;
    auto alloc = [&](size_t bytes) -> void* {
        void* p = w + off;
        off += (bytes + 255) & ~(size_t)255;
        return p;
    };
    uint2* tuples   = (uint2*)alloc(n_pairs * sizeof(uint2));
    int*   blk_hist = (int*)  alloc((size_t)nb * NBLK * sizeof(int));
    int*   offs     = (int*)  alloc((size_t)nb * NBLK * sizeof(int));
    int*   totals   = (int*)  alloc((size_t)nb * sizeof(int));
    int*   bases    = (int*)  alloc((size_t)nb * sizeof(int));

    // adaptive slice count: partials = nb*nslice*A_B*4*4 bytes
    size_t slice_bytes = (size_t)nb * A_B * 4 * sizeof(float);
    int nslice = 16;
    while (nslice > 1 && off + (size_t)nslice * slice_bytes > ws_size) nslice >>= 1;
    float* partials = (float*)alloc((size_t)nslice * slice_bytes);

    if (off <= ws_size && nb <= MAXNB) {
        k_hist   <<<NBLK, BLOCK, 0, stream>>>(nbr, blk_hist, n_edges, nb);
        k_rowscan<<<nb,   NBLK,  0, stream>>>(blk_hist, offs, totals);
        k_bases  <<<1,    MAXNB, 0, stream>>>(totals, bases, nb);
        k_addbase<<<(nb * NBLK + 255) / 256, 256, 0, stream>>>(offs, bases, nb * NBLK);
        k_scatter<<<NBLK, BLOCK, 0, stream>>>(nbr, dist, offs, tuples, n_edges, nb);
        k_accum  <<<nb * nslice, BLOCK, 0, stream>>>(tuples, charges, bases, totals,
                                                     (float4*)partials, nslice);
        k_final  <<<(n_atoms + 255) / 256, 256, 0, stream>>>(
            (const float4*)partials, (float4*)d_out, n_atoms, nslice);
    } else {
        hipMemsetAsync(d_out, 0, (size_t)out_size * sizeof(float), stream);
        edge_scatter_agent<<<(n_edges + BLOCK - 1) / BLOCK, BLOCK, 0, stream>>>(
            charges, nbr, dist, (float*)d_out, n_edges);
    }
}

// Round 2
// 1036.249 us; speedup vs baseline: 1.0029x; 1.0029x over previous
//
#include <hip/hip_runtime.h>

// Counting-sort + LDS accumulation (no global atomics anywhere).
// R5 -> R6: k_accum was bound by per-CU L1 miss concurrency on random 16B
// charges gathers (13.4 cy/tuple == ~16 misses in flight @ ~220 cy L2 lat;
// insensitive to MLP/layout changes R4==R5). Fix: eliminate the gathers.
//   - pass B: per-dst-bucket chunked counting sort by SRC bucket (k_hist2,
//     k_scan2, k_scat2) -> tuples grouped into (dst,src) tiles.
//   - k_accum3: per (dst, src-slice) block stages each 16KB src bucket into
//     LDS with coalesced loads (reg-prefetch T14 split), gather -> LDS read.
//   - partials alias dead tuplesA region; R5 single-pass path kept as
//     fallback when ws_size can't hold both tuple arrays.

#define BLOCK   256
#define NBLK    1024       // edge chunks for hist/scatter (== rowscan width)
#define NBLK_LG 10
#define AB_LOG  10
#define A_B     1024       // atoms per bucket
#define PLANE   1056       // acc plane stride (spreads ds_add over 32 banks)
#define MAXNB   256
#define CH      8          // pass-B chunks per dst bucket
#define SRC_PER 14         // src buckets per k_accum3 block

static __device__ __forceinline__ unsigned long long nt_u64(const void* p) {
    return __builtin_nontemporal_load((const unsigned long long*)p);
}
static __device__ __forceinline__ float nt_f32(const float* p) {
    return __builtin_nontemporal_load(p);
}
typedef float v4f __attribute__((ext_vector_type(4)));
static __device__ __forceinline__ void nt_store_f4(float4 v, float4* p) {
    v4f x; x.x = v.x; x.y = v.y; x.z = v.z; x.w = v.w;
    __builtin_nontemporal_store(x, (v4f*)p);
}

// ---- K1: per-block histogram over dst buckets ---------------------------
__global__ __launch_bounds__(BLOCK) void k_hist(
    const int2* __restrict__ nbr, int* __restrict__ blk_hist,
    int n_edges, int nb)
{
    __shared__ int h[MAXNB];
    for (int i = threadIdx.x; i < nb; i += blockDim.x) h[i] = 0;
    __syncthreads();
    int per = (n_edges + gridDim.x - 1) / gridDim.x;
    int lo = blockIdx.x * per;
    int hi = min(lo + per, n_edges);
    #pragma unroll 4
    for (int e = lo + threadIdx.x; e < hi; e += blockDim.x) {
        unsigned long long v = nt_u64(&nbr[e]);
        int ix = (int)(v & 0xffffffffu);
        int iy = (int)(v >> 32);
        atomicAdd(&h[ix >> AB_LOG], 1);
        atomicAdd(&h[iy >> AB_LOG], 1);
    }
    __syncthreads();
    for (int i = threadIdx.x; i < nb; i += blockDim.x)
        blk_hist[i * NBLK + blockIdx.x] = h[i];
}

// ---- K2: exclusive scan of each bucket's row (NBLK entries) -------------
__global__ __launch_bounds__(NBLK) void k_rowscan(
    const int* __restrict__ blk_hist, int* __restrict__ offs,
    int* __restrict__ totals)
{
    __shared__ int a[NBLK];
    int b = blockIdx.x, t = threadIdx.x;
    int v = blk_hist[b * NBLK + t];
    a[t] = v;
    __syncthreads();
    for (int off = 1; off < NBLK; off <<= 1) {
        int x = (t >= off) ? a[t - off] : 0;
        __syncthreads();
        a[t] += x;
        __syncthreads();
    }
    offs[b * NBLK + t] = a[t] - v;       // exclusive within bucket
    if (t == NBLK - 1) totals[b] = a[t];
}

// ---- K3: bucket bases (parallel LDS scan, one block) --------------------
__global__ __launch_bounds__(MAXNB) void k_bases(
    const int* __restrict__ totals, int* __restrict__ bases, int nb)
{
    __shared__ int a[MAXNB];
    int t = threadIdx.x;
    int v = (t < nb) ? totals[t] : 0;
    a[t] = v;
    __syncthreads();
    for (int off = 1; off < MAXNB; off <<= 1) {
        int x = (t >= off) ? a[t - off] : 0;
        __syncthreads();
        a[t] += x;
        __syncthreads();
    }
    if (t < nb) bases[t] = a[t] - v;
}

// ---- K4: offs[i] += bases[i / NBLK] -------------------------------------
__global__ void k_addbase(int* __restrict__ offs, const int* __restrict__ bases, int n)
{
    int i = blockIdx.x * blockDim.x + threadIdx.x;
    if (i < n) offs[i] += bases[i >> NBLK_LG];
}

// ---- K5: counting-sort scatter of tuples (by dst bucket) ----------------
// tuple.x = dst_local(10b) | src_global(18b)<<10 ; tuple.y = w bits
__global__ __launch_bounds__(BLOCK) void k_scatter(
    const int2* __restrict__ nbr, const float* __restrict__ dist,
    const int* __restrict__ offs, uint2* __restrict__ tuples,
    int n_edges, int nb)
{
    __shared__ int cur[MAXNB];
    for (int i = threadIdx.x; i < nb; i += blockDim.x)
        cur[i] = offs[i * NBLK + blockIdx.x];
    __syncthreads();
    int per = (n_edges + gridDim.x - 1) / gridDim.x;
    int lo = blockIdx.x * per;
    int hi = min(lo + per, n_edges);
    #pragma unroll 2
    for (int e = lo + threadIdx.x; e < hi; e += blockDim.x) {
        unsigned long long v = nt_u64(&nbr[e]);
        int ix = (int)(v & 0xffffffffu);
        int iy = (int)(v >> 32);
        float w = 0.5f / nt_f32(&dist[e]);
        unsigned wb = __float_as_uint(w);
        int pi = atomicAdd(&cur[ix >> AB_LOG], 1);
        tuples[pi] = make_uint2((unsigned)(ix & (A_B - 1)) | ((unsigned)iy << AB_LOG), wb);
        int pj = atomicAdd(&cur[iy >> AB_LOG], 1);
        tuples[pj] = make_uint2((unsigned)(iy & (A_B - 1)) | ((unsigned)ix << AB_LOG), wb);
    }
}

// ---- K6: pass-B histogram: per (dst bucket, chunk) count src buckets ----
__global__ __launch_bounds__(BLOCK) void k_hist2(
    const uint2* __restrict__ tuplesA, const int* __restrict__ bases,
    const int* __restrict__ totals, int* __restrict__ hist2, int nb)
{
    __shared__ int h[MAXNB];
    int b = blockIdx.x / CH, c = blockIdx.x % CH;
    for (int i = threadIdx.x; i < nb; i += BLOCK) h[i] = 0;
    __syncthreads();
    int bs = bases[b], cnt = totals[b];
    int lo = bs + (int)((long long)cnt * c / CH);
    int hi = bs + (int)((long long)cnt * (c + 1) / CH);
    #pragma unroll 4
    for (int p = lo + threadIdx.x; p < hi; p += BLOCK) {
        unsigned long long t = nt_u64(&tuplesA[p]);
        atomicAdd(&h[(unsigned)(t & 0xffffffffu) >> 20], 1);   // src bucket
    }
    __syncthreads();
    for (int i = threadIdx.x; i < nb; i += BLOCK)
        hist2[(b * CH + c) * nb + i] = h[i];
}

// ---- K7: per-dst-bucket scan over (src-major, chunk-minor) --------------
__global__ __launch_bounds__(BLOCK) void k_scan2(
    const int* __restrict__ hist2, int* __restrict__ offs2, int nb)
{
    __shared__ int sums[BLOCK];
    int b = blockIdx.x, t = threadIdx.x;
    int v[CH];
    int tot = 0;
    if (t < nb) {
        #pragma unroll
        for (int c = 0; c < CH; ++c) {
            int x = hist2[(b * CH + c) * nb + t];
            v[c] = tot; tot += x;
        }
    }
    sums[t] = (t < nb) ? tot : 0;
    __syncthreads();
    for (int off = 1; off < BLOCK; off <<= 1) {
        int x = (t >= off) ? sums[t - off] : 0;
        __syncthreads();
        sums[t] += x;
        __syncthreads();
    }
    if (t < nb) {
        int prefix = (t == 0) ? 0 : sums[t - 1];
        #pragma unroll
        for (int c = 0; c < CH; ++c)
            offs2[(size_t)b * nb * CH + t * CH + c] = prefix + v[c];
    }
}

// ---- K8: pass-B scatter: stable sort bucket tuples by src bucket --------
__global__ __launch_bounds__(BLOCK) void k_scat2(
    const uint2* __restrict__ tuplesA, const int* __restrict__ bases,
    const int* __restrict__ totals, const int* __restrict__ offs2,
    uint2* __restrict__ tuplesB, int nb)
{
    __shared__ int cur[MAXNB];
    int b = blockIdx.x / CH, c = blockIdx.x % CH;
    for (int i = threadIdx.x; i < nb; i += BLOCK)
        cur[i] = offs2[(size_t)b * nb * CH + i * CH + c];
    __syncthreads();
    int bs = bases[b], cnt = totals[b];
    int lo = bs + (int)((long long)cnt * c / CH);
    int hi = bs + (int)((long long)cnt * (c + 1) / CH);
    #pragma unroll 2
    for (int p = lo + threadIdx.x; p < hi; p += BLOCK) {
        unsigned long long t = nt_u64(&tuplesA[p]);
        unsigned x = (unsigned)(t & 0xffffffffu);
        int s = (int)(x >> 20);
        int pos = atomicAdd(&cur[s], 1);
        tuplesB[bs + pos] = make_uint2(x, (unsigned)(t >> 32));
    }
}

// ---- K9: tiled accumulation: src bucket staged in LDS (no gathers) ------
__global__ __launch_bounds__(BLOCK) void k_accum3(
    const uint2* __restrict__ tuplesB, const float4* __restrict__ charges,
    const int* __restrict__ bases, const int* __restrict__ totals,
    const int* __restrict__ offs2, float4* __restrict__ partials,
    int nb, int nsl, int n_atoms)
{
    __shared__ float  acc[4 * PLANE];    // 16.9 KB, plane-major
    __shared__ float4 stg[A_B];          // 16 KB staged src charges
    int b = blockIdx.x / nsl, sl = blockIdx.x % nsl;
    for (int i = threadIdx.x; i < 4 * PLANE; i += BLOCK) acc[i] = 0.f;
    int bs = bases[b], cnt = totals[b];
    int s0 = sl * SRC_PER;
    int s1 = min(s0 + SRC_PER, nb);
    const int* o2 = offs2 + (size_t)b * nb * CH;
    float4 z = make_float4(0.f, 0.f, 0.f, 0.f);

    // initial stage of src bucket s0 (coalesced)
    {
        int abase = s0 << AB_LOG, lim = n_atoms - abase;
        #pragma unroll
        for (int r = 0; r < A_B / BLOCK; ++r) {
            int i = threadIdx.x + r * BLOCK;
            stg[i] = (i < lim) ? charges[abase + i] : z;
        }
    }
    __syncthreads();

    for (int s = s0; s < s1; ++s) {
        // T14 split: issue next-bucket loads now, write to LDS after barrier
        float4 pre0, pre1, pre2, pre3;
        bool more = (s + 1 < s1);
        if (more) {
            int abase = (s + 1) << AB_LOG, lim = n_atoms - abase;
            int i0 = threadIdx.x;
            pre0 = (i0 < lim)             ? charges[abase + i0]             : z;
            pre1 = (i0 + BLOCK < lim)     ? charges[abase + i0 + BLOCK]     : z;
            pre2 = (i0 + 2 * BLOCK < lim) ? charges[abase + i0 + 2 * BLOCK] : z;
            pre3 = (i0 + 3 * BLOCK < lim) ? charges[abase + i0 + 3 * BLOCK] : z;
        }
        int lo = bs + o2[s * CH];
        int hi = (s + 1 < nb) ? bs + o2[(s + 1) * CH] : bs + cnt;
        #pragma unroll 2
        for (int p = lo + threadIdx.x; p < hi; p += BLOCK) {
            unsigned long long t = nt_u64(&tuplesB[p]);
            unsigned x = (unsigned)(t & 0xffffffffu);
            float wgt = __uint_as_float((unsigned)(t >> 32));
            float4 c = stg[(x >> AB_LOG) & (A_B - 1)];
            int d = (int)(x & (A_B - 1));
            atomicAdd(&acc[d],             c.x * wgt);
            atomicAdd(&acc[PLANE + d],     c.y * wgt);
            atomicAdd(&acc[2 * PLANE + d], c.z * wgt);
            atomicAdd(&acc[3 * PLANE + d], c.w * wgt);
        }
        __syncthreads();
        if (more) {
            stg[threadIdx.x]             = pre0;
            stg[threadIdx.x + BLOCK]     = pre1;
            stg[threadIdx.x + 2 * BLOCK] = pre2;
            stg[threadIdx.x + 3 * BLOCK] = pre3;
        }
        __syncthreads();
    }
    float4* outp = partials + (size_t)blockIdx.x * A_B;
    for (int i = threadIdx.x; i < A_B; i += BLOCK) {
        float4 v = make_float4(acc[i], acc[PLANE + i],
                               acc[2 * PLANE + i], acc[3 * PLANE + i]);
        nt_store_f4(v, &outp[i]);
    }
}

// ---- K6 (legacy R5): gather-based accumulation (ws-tight fallback) ------
__global__ __launch_bounds__(BLOCK) void k_accum(
    const uint2* __restrict__ tuples, const float4* __restrict__ charges,
    const int* __restrict__ bases, const int* __restrict__ totals,
    float4* __restrict__ partials, int nslice)
{
    __shared__ float acc[4 * PLANE];
    int b = blockIdx.x / nslice;
    int s = blockIdx.x - b * nslice;
    for (int i = threadIdx.x; i < 4 * PLANE; i += BLOCK) acc[i] = 0.f;
    __syncthreads();
    int start = bases[b], cnt = totals[b];
    int lo = start + (int)((long long)cnt * s / nslice);
    int hi = start + (int)((long long)cnt * (s + 1) / nslice);
    const int T = 8;
    int p = lo + threadIdx.x;
    for (; p + (T - 1) * BLOCK < hi; p += T * BLOCK) {
        unsigned long long t[T];
        float4 c[T];
        #pragma unroll
        for (int k = 0; k < T; ++k) t[k] = nt_u64(&tuples[p + k * BLOCK]);
        #pragma unroll
        for (int k = 0; k < T; ++k)
            c[k] = charges[(unsigned)(t[k] & 0xffffffffu) >> AB_LOG];
        #pragma unroll
        for (int k = 0; k < T; ++k) {
            float w = __uint_as_float((unsigned)(t[k] >> 32));
            int d = (int)(t[k] & (A_B - 1));
            atomicAdd(&acc[d],             c[k].x * w);
            atomicAdd(&acc[PLANE + d],     c[k].y * w);
            atomicAdd(&acc[2 * PLANE + d], c[k].z * w);
            atomicAdd(&acc[3 * PLANE + d], c[k].w * w);
        }
    }
    for (; p < hi; p += BLOCK) {
        unsigned long long t = nt_u64(&tuples[p]);
        float4 c = charges[(unsigned)(t & 0xffffffffu) >> AB_LOG];
        float w = __uint_as_float((unsigned)(t >> 32));
        int d = (int)(t & (A_B - 1));
        atomicAdd(&acc[d],             c.x * w);
        atomicAdd(&acc[PLANE + d],     c.y * w);
        atomicAdd(&acc[2 * PLANE + d], c.z * w);
        atomicAdd(&acc[3 * PLANE + d], c.w * w);
    }
    __syncthreads();
    float4* outp = partials + (size_t)blockIdx.x * A_B;
    for (int i = threadIdx.x; i < A_B; i += BLOCK) {
        float4 v = make_float4(acc[i], acc[PLANE + i],
                               acc[2 * PLANE + i], acc[3 * PLANE + i]);
        nt_store_f4(v, &outp[i]);
    }
}

// ---- K10: reduce partial images -> out ----------------------------------
__global__ void k_final(const float4* __restrict__ partials,
                        float4* __restrict__ out, int n_atoms, int nslice)
{
    int a = blockIdx.x * blockDim.x + threadIdx.x;
    if (a >= n_atoms) return;
    int b = a >> AB_LOG;
    int local = a & (A_B - 1);
    const float4* p = partials + (size_t)(b * nslice) * A_B + local;
    float4 r = make_float4(0.f, 0.f, 0.f, 0.f);
    for (int s = 0; s < nslice; ++s) {
        float4 t = p[(size_t)s * A_B];
        r.x += t.x; r.y += t.y; r.z += t.z; r.w += t.w;
    }
    out[a] = r;
}

// ---- fallback (ws too small even for R5): agent-scope atomics -----------
__global__ __launch_bounds__(BLOCK) void edge_scatter_agent(
    const float4* __restrict__ charges, const int2* __restrict__ nbr,
    const float* __restrict__ dist, float* __restrict__ out, int n_edges)
{
    int e = blockIdx.x * blockDim.x + threadIdx.x;
    if (e >= n_edges) return;
    int2 ij = nbr[e];
    float w = 0.5f / dist[e];
    float4 cj = charges[ij.y];
    float4 ci = charges[ij.x];
    float* oi = out + (size_t)ij.x * 4;
    float* oj = out + (size_t)ij.y * 4;
    atomicAdd(oi + 0, cj.x * w); atomicAdd(oi + 1, cj.y * w);
    atomicAdd(oi + 2, cj.z * w); atomicAdd(oi + 3, cj.w * w);
    atomicAdd(oj + 0, ci.x * w); atomicAdd(oj + 1, ci.y * w);
    atomicAdd(oj + 2, ci.z * w); atomicAdd(oj + 3, ci.w * w);
}

extern "C" void kernel_launch(void* const* d_in, const int* in_sizes, int n_in,
                              void* d_out, int out_size, void* d_ws, size_t ws_size,
                              hipStream_t stream)
{
    const float4* charges = (const float4*)d_in[0];
    const int2*   nbr     = (const int2*)d_in[3];
    const float*  dist    = (const float*)d_in[4];

    int n_edges = in_sizes[4];
    int n_atoms = out_size / 4;
    int nb = (n_atoms + A_B - 1) >> AB_LOG;     // 196 for 200000 atoms

    size_t n_pairs = (size_t)2 * n_edges;
    char*  w = (char*)d_ws;
    auto align256 = [](size_t x) { return (x + 255) & ~(size_t)255; };

    // ---- two-pass layout ----
    size_t szA    = n_pairs * sizeof(uint2);
    size_t szHist = (size_t)nb * NBLK * sizeof(int);
    int    nsl    = (nb + SRC_PER - 1) / SRC_PER;
    size_t szPart2 = (size_t)nb * nsl * A_B * sizeof(float4);

    size_t off = 0;
    size_t oA   = off; off += align256(szA);
    size_t oB   = off; off += align256(szA);
    size_t oBH  = off; off += align256(szHist);
    size_t oOf  = off; off += align256(szHist);
    size_t oTot = off; off += align256((size_t)nb * sizeof(int));
    size_t oBas = off; off += align256((size_t)nb * sizeof(int));
    size_t oH2  = off; off += align256((size_t)nb * CH * nb * sizeof(int));
    size_t oO2  = off; off += align256((size_t)nb * nb * CH * sizeof(int));
    bool two_ok = (off <= ws_size) && (nb <= MAXNB) && (szPart2 <= szA);

    if (two_ok) {
        uint2* tuplesA  = (uint2*)(w + oA);
        uint2* tuplesB  = (uint2*)(w + oB);
        int*   blk_hist = (int*)(w + oBH);
        int*   offs     = (int*)(w + oOf);
        int*   totals   = (int*)(w + oTot);
        int*   bases    = (int*)(w + oBas);
        int*   hist2    = (int*)(w + oH2);
        int*   offs2    = (int*)(w + oO2);
        float4* partials = (float4*)(w + oA);   // alias tuplesA (dead after k_scat2)

        k_hist   <<<NBLK, BLOCK, 0, stream>>>(nbr, blk_hist, n_edges, nb);
        k_rowscan<<<nb,   NBLK,  0, stream>>>(blk_hist, offs, totals);
        k_bases  <<<1,    MAXNB, 0, stream>>>(totals, bases, nb);
        k_addbase<<<(nb * NBLK + 255) / 256, 256, 0, stream>>>(offs, bases, nb * NBLK);
        k_scatter<<<NBLK, BLOCK, 0, stream>>>(nbr, dist, offs, tuplesA, n_edges, nb);
        k_hist2  <<<nb * CH, BLOCK, 0, stream>>>(tuplesA, bases, totals, hist2, nb);
        k_scan2  <<<nb,      BLOCK, 0, stream>>>(hist2, offs2, nb);
        k_scat2  <<<nb * CH, BLOCK, 0, stream>>>(tuplesA, bases, totals, offs2, tuplesB, nb);
        k_accum3 <<<nb * nsl, BLOCK, 0, stream>>>(tuplesB, charges, bases, totals, offs2,
                                                  partials, nb, nsl, n_atoms);
        k_final  <<<(n_atoms + 255) / 256, 256, 0, stream>>>(
            partials, (float4*)d_out, n_atoms, nsl);
        return;
    }

    // ---- R5 single-pass layout (fallback) ----
    off = 0;
    auto alloc = [&](size_t bytes) -> void* {
        void* p = w + off;
        off += align256(bytes);
        return p;
    };
    uint2* tuples   = (uint2*)alloc(n_pairs * sizeof(uint2));
    int*   blk_hist = (int*)  alloc(szHist);
    int*   offs     = (int*)  alloc(szHist);
    int*   totals   = (int*)  alloc((size_t)nb * sizeof(int));
    int*   bases    = (int*)  alloc((size_t)nb * sizeof(int));
    size_t slice_bytes = (size_t)nb * A_B * 4 * sizeof(float);
    int nslice = 16;
    while (nslice > 1 && off + (size_t)nslice * slice_bytes > ws_size) nslice >>= 1;
    float* partials = (float*)alloc((size_t)nslice * slice_bytes);

    if (off <= ws_size && nb <= MAXNB) {
        k_hist   <<<NBLK, BLOCK, 0, stream>>>(nbr, blk_hist, n_edges, nb);
        k_rowscan<<<nb,   NBLK,  0, stream>>>(blk_hist, offs, totals);
        k_bases  <<<1,    MAXNB, 0, stream>>>(totals, bases, nb);
        k_addbase<<<(nb * NBLK + 255) / 256, 256, 0, stream>>>(offs, bases, nb * NBLK);
        k_scatter<<<NBLK, BLOCK, 0, stream>>>(nbr, dist, offs, tuples, n_edges, nb);
        k_accum  <<<nb * nslice, BLOCK, 0, stream>>>(tuples, charges, bases, totals,
                                                     (float4*)partials, nslice);
        k_final  <<<(n_atoms + 255) / 256, 256, 0, stream>>>(
            (const float4*)partials, (float4*)d_out, n_atoms, nslice);
    } else {
        hipMemsetAsync(d_out, 0, (size_t)out_size * sizeof(float), stream);
        edge_scatter_agent<<<(n_edges + BLOCK - 1) / BLOCK, BLOCK, 0, stream>>>(
            charges, nbr, dist, (float*)d_out, n_edges);
    }
}